// Round 5
// baseline (178.213 us; speedup 1.0000x reference)
//
#include <hip/hip_runtime.h>
#include <hip/hip_bf16.h>

// Problem constants (B,T,C,H) = (8,1024,768,12), D=64
#define Bb 8
#define Tt 1024
#define Cc 768
#define Hh 12
#define Dd 64
#define M_ROWS (Bb * Tt)      // 8192
#define QKV_N (3 * Cc)        // 2304

typedef __attribute__((ext_vector_type(8))) short s16x8;   // 8 x bf16
typedef __attribute__((ext_vector_type(4))) short s16x4;   // 4 x bf16
typedef __attribute__((ext_vector_type(4))) float f32x4;

#define AS1 __attribute__((address_space(1)))
#define AS3 __attribute__((address_space(3)))

template <int V> struct IC { static constexpr int value = V; };

static __device__ __forceinline__ short f2bf(float f) {
    union { float f; unsigned u; } v; v.f = f;
    unsigned r = (v.u + 0x7fffu + ((v.u >> 16) & 1u)) >> 16;  // RNE
    return (short)r;
}
// two f32 -> packed bf16x2 (TRUNCATION) in one v_perm_b32
static __device__ __forceinline__ unsigned pkt(float hi, float lo) {
    union { float f; unsigned u; } a, b; a.f = hi; b.f = lo;
    return __builtin_amdgcn_perm(a.u, b.u, 0x07060302u);
}

// ---------------------------------------------------------------------------
// Prep: fp32->bf16 casts + RoPE cos/sin table, one launch.
// wqkv rows are PERMUTED for q/k sections (sigma = row^0x30 for within-head
// quadrants 1,2): RoPE partners (i,i+32) become ADJACENT 16-col tiles in the
// qkv output, so any 32-col-aligned wave tile holds complete rotation pairs.
// Q.K is invariant (same sigma on q and k); v rows untouched.
// ---------------------------------------------------------------------------
static __device__ __forceinline__ void cast8(const float* __restrict__ in,
                                             short* __restrict__ out, int i) {
    const float4 a = ((const float4*)in)[i * 2];
    const float4 b = ((const float4*)in)[i * 2 + 1];
    s16x8 f;
    f[0] = f2bf(a.x); f[1] = f2bf(a.y); f[2] = f2bf(a.z); f[3] = f2bf(a.w);
    f[4] = f2bf(b.x); f[5] = f2bf(b.y); f[6] = f2bf(b.z); f[7] = f2bf(b.w);
    ((s16x8*)out)[i] = f;
}

#define S1 (M_ROWS * Cc / 8)   // 786432
#define S2 (QKV_N * Cc / 8)    // 221184
#define S3 (Cc * Cc / 8)       // 73728
#define SROPE (Tt * 32)        // 32768
#define PREP_THREADS (S1 + S2 + S3 + SROPE)  // 1114112 = 4352 * 256

__global__ __launch_bounds__(256) void prep_kernel(const float* __restrict__ x,
                                                   const float* __restrict__ wqkv,
                                                   const float* __restrict__ wproj,
                                                   short* __restrict__ xb,
                                                   short* __restrict__ wqkvb,
                                                   short* __restrict__ wprojb,
                                                   float2* __restrict__ cs) {
    int idx = blockIdx.x * blockDim.x + threadIdx.x;
    if (idx < S1) { cast8(x, xb, idx); return; }
    idx -= S1;
    if (idx < S2) {
        // permuted cast for wqkv: position-row n holds original row tau(n)
        int row = idx / 96;          // 768/8 = 96 chunks per row
        int c8  = idx - row * 96;
        int q2 = (row >> 4) & 3;
        int src = (row < 2 * Cc && (q2 == 1 || q2 == 2)) ? (row ^ 0x30) : row;
        const float4 a = ((const float4*)(wqkv + (size_t)src * Cc))[c8 * 2];
        const float4 b = ((const float4*)(wqkv + (size_t)src * Cc))[c8 * 2 + 1];
        s16x8 f;
        f[0] = f2bf(a.x); f[1] = f2bf(a.y); f[2] = f2bf(a.z); f[3] = f2bf(a.w);
        f[4] = f2bf(b.x); f[5] = f2bf(b.y); f[6] = f2bf(b.z); f[7] = f2bf(b.w);
        ((s16x8*)wqkvb)[idx] = f;
        return;
    }
    idx -= S2;
    if (idx < S3) { cast8(wproj, wprojb, idx); return; }
    idx -= S3;
    {
        int t = idx >> 5, i = idx & 31;
        float inv_freq = exp2f(-0.41524101186092037f * (float)i);  // log2(1e4)/32
        float fr = (float)t * inv_freq;
        float2 v; v.x = cosf(fr); v.y = sinf(fr);
        cs[idx] = v;
    }
}

// ---------------------------------------------------------------------------
// bf16 MFMA GEMM (NT) — retained for the PROJ gemm only (MODE 0, TN=96).
// ---------------------------------------------------------------------------
template <int MODE, int TN>
__global__ __launch_bounds__(256, 3) void gemm_nt_mfma(const short* __restrict__ A,
                                                       const short* __restrict__ B,
                                                       void* __restrict__ Cout,
                                                       const float2* __restrict__ cs,
                                                       int M, int N, int K, int nblocks) {
    __shared__ short As[2][128 * 32];
    __shared__ short Bs[2][TN * 32];
    constexpr int NTW = TN / 32;   // col-tiles per wave

    const int wave = threadIdx.x >> 6;
    const int lane = threadIdx.x & 63;
    const int l16  = lane & 15;
    const int quad = lane >> 4;
    const int wr = wave >> 1;      // 0,1 row half
    const int wc = wave & 1;       // 0,1 col half

    // XCD-aware swizzle (M/128 divisible by 8)
    const int mb8  = (M >> 7) >> 3;
    const int xcd  = blockIdx.x & 7;
    const int slot = blockIdx.x >> 3;
    const int bm = (xcd * mb8 + slot / nblocks) * 128;
    const int bn = (slot % nblocks) * TN;

    f32x4 acc[4][NTW] = {};

    auto stage = [&](int k0, int buf) {
#pragma unroll
        for (int j = 0; j < 2; j++) {                 // A: 512 chunks
            const int D = j * 256 + wave * 64 + lane;
            const int G = D >> 3;
            const int s = (G << 3) | ((D & 7) ^ (G & 7));
            const int m = s >> 2, c4 = (s & 3) * 8;
            __builtin_amdgcn_global_load_lds(
                (const AS1 unsigned*)(A + (size_t)(bm + m) * K + k0 + c4),
                (AS3 unsigned*)&As[buf][(j * 256 + wave * 64) * 8], 16, 0, 0);
        }
        constexpr int BCH = TN * 4;                   // B chunks
#pragma unroll
        for (int j = 0; j < (BCH + 255) / 256; j++) {
            if (BCH % 256 == 0 || j * 256 + wave * 64 < BCH) {  // wave-uniform
                const int D = j * 256 + wave * 64 + lane;
                const int G = D >> 3;
                const int s = (G << 3) | ((D & 7) ^ (G & 7));
                const int m = s >> 2, c4 = (s & 3) * 8;
                __builtin_amdgcn_global_load_lds(
                    (const AS1 unsigned*)(B + (size_t)(bn + m) * K + k0 + c4),
                    (AS3 unsigned*)&Bs[buf][(j * 256 + wave * 64) * 8], 16, 0, 0);
            }
        }
    };

    const int nIter = K >> 5;   // K/32
    stage(0, 0);
    for (int kt = 0; kt < nIter; kt++) {
        const int buf = kt & 1;
        __syncthreads();                       // drains loads for tile kt
        if (kt + 1 < nIter) stage((kt + 1) << 5, buf ^ 1);

        s16x8 af[4];
#pragma unroll
        for (int mt = 0; mt < 4; mt++) {
            const int m = wr * 64 + mt * 16 + l16;
            const int d = ((m & 1) * 4 + quad) ^ ((m >> 1) & 7);
            af[mt] = *(const s16x8*)&As[buf][(m >> 1) * 64 + d * 8];
        }
#pragma unroll
        for (int nt = 0; nt < NTW; nt++) {
            const int n = wc * (TN / 2) + nt * 16 + l16;
            const int d = ((n & 1) * 4 + quad) ^ ((n >> 1) & 7);
            s16x8 bf = *(const s16x8*)&Bs[buf][(n >> 1) * 64 + d * 8];
#pragma unroll
            for (int mt = 0; mt < 4; mt++)
                acc[mt][nt] = __builtin_amdgcn_mfma_f32_16x16x32_bf16(
                    af[mt], bf, acc[mt][nt], 0, 0, 0);
        }
    }

    if constexpr (MODE == 0) {
#pragma unroll
        for (int mt = 0; mt < 4; mt++)
#pragma unroll
            for (int r = 0; r < 4; r++) {
                const size_t row = bm + wr * 64 + mt * 16 + quad * 4 + r;
#pragma unroll
                for (int nt = 0; nt < NTW; nt++)
                    ((float*)Cout)[row * N + bn + wc * (TN / 2) + nt * 16 + l16] =
                        acc[mt][nt][r];
            }
    } else {
        const bool is_v = (bn >= 2 * Cc);
        if (is_v) {
#pragma unroll
            for (int mt = 0; mt < 4; mt++)
#pragma unroll
                for (int r = 0; r < 4; r++) {
                    const size_t row = bm + wr * 64 + mt * 16 + quad * 4 + r;
#pragma unroll
                    for (int nt = 0; nt < NTW; nt++)
                        ((short*)Cout)[row * N + bn + wc * (TN / 2) + nt * 16 + l16] =
                            f2bf(acc[mt][nt][r]);
                }
        } else {
            const float scale = (bn < Cc) ? 0.125f : 1.0f;  // q gets 1/sqrt(D)
#pragma unroll
            for (int mt = 0; mt < 4; mt++) {
#pragma unroll
                for (int r = 0; r < 4; r++) {
                    const int row = bm + wr * 64 + mt * 16 + quad * 4 + r;
                    const int t = row & (Tt - 1);
                    short* cp = (short*)Cout + (size_t)row * N + bn + wc * (TN / 2);
#pragma unroll
                    for (int p = 0; p < NTW; p += 2) {   // adjacent-tile pairs
                        const int g = wc * NTW + p;       // global col-tile (even)
                        const int i0 = ((g & 2) ? 16 : 0) + l16;
                        const float2 c0 = cs[t * 32 + i0];
                        const float x1 = acc[mt][p][r];
                        const float x2 = acc[mt][p + 1][r];
                        cp[p * 16 + l16]        = f2bf((x1 * c0.x + x2 * c0.y) * scale);
                        cp[(p + 1) * 16 + l16]  = f2bf((-x1 * c0.y + x2 * c0.x) * scale);
                    }
                }
            }
        }
    }
}

// ---------------------------------------------------------------------------
// QKV GEMM v4 — faithful m201-style fine-phase schedule.
//   R2/R3 post-mortem: counted vmcnt with ONE barrier per K-tile is the
//   null quadrant (8-phase-with-drain ≈ 1-phase, m218); the prerequisite
//   is the per-phase barrier-pair alternation. This version:
//     BM=256 x BN=288, grid 32x8 = 256 blocks = 1/CU (m201's residency),
//     512 threads (8 waves 4x2; per-wave 64x144 = 4mt x 9nt).
//     BK=32, THREE buffers (102 KiB), 2-deep prefetch, publish via
//     COUNTED vmcnt(5); drain-to-0 only at tail.
//     2 phases/K-tile, 4 barriers/K-tile:
//       phase = { issue 2-3 gloads(kt+2) ; ds_read subtile ; s_barrier ;
//                 sched_barrier(0) ; setprio(1) 18 MFMA setprio(0) ;
//                 s_barrier }
//     B-frags read once per K-tile (phase A), held in 36 VGPR.
//   XCD ROW-stripe map (col-panel map cost FETCH 21->92 MB in R2).
//   Epilogue: R2's verified rule-#20-clean orphan-pair exchange.
//   PRE-COMMIT: if this lands >= 43us, fine-phase is null on this shape;
//   abandon GEMM pipelining permanently.
// ---------------------------------------------------------------------------
#define QBM 256
#define QBN 288

__global__ __launch_bounds__(512, 1) void qkv_gemm_fine(const short* __restrict__ A,
                                                        const short* __restrict__ Bw,
                                                        short* __restrict__ Cq,
                                                        const float2* __restrict__ cs) {
    __shared__ short As[3][QBM * 32];   // 3 x 16 KiB
    __shared__ short Bs[3][QBN * 32];   // 3 x 18 KiB   (total 104448 B)

    const int tid  = threadIdx.x;
    const int wave = tid >> 6;
    const int lane = tid & 63;
    const int l16  = lane & 15;
    const int quad = lane >> 4;
    const int wr   = wave >> 1;         // 0..3 -> 64-row band
    const int wc   = wave & 1;          // 0..1 -> 144-col half

    // XCD row-stripe map: 256 blocks = 32 row-tiles x 8 col-panels.
    const int xcd  = blockIdx.x & 7;
    const int slot = blockIdx.x >> 3;   // 0..31
    const int bm   = (xcd * 4 + (slot >> 3)) * QBM;
    const int bn   = (slot & 7) * QBN;
    const int gt0  = (slot & 7) * 18;   // global col-tile base

    // staging source offsets (elements)
    int aoff0, boffR;
    {
        const int G = tid >> 3;
        const int s = (G << 3) | ((tid & 7) ^ (G & 7));
        aoff0 = (s >> 2) * Cc + (s & 3) * 8;      // also B main offset
    }
    {
        const int D = 1024 + (wave & 1) * 64 + lane;   // B remainder (4x dup)
        const int G = D >> 3;
        const int s = (G << 3) | ((D & 7) ^ (G & 7));
        boffR = (s >> 2) * Cc + (s & 3) * 8;
    }
    const short* Ag = A + (size_t)bm * Cc;
    const short* Bg = Bw + (size_t)bn * Cc;

    // fragment LDS byte offsets (swizzled, 2 rows per 128B line)
    const int mA = wr * 64 + l16;
    const int abase = (mA >> 1) * 128 + ((((mA & 1) * 4 + quad) ^ ((mA >> 1) & 7)) * 16);
    const int nB = wc * 144 + l16;
    const int bbase = (nB >> 1) * 128 + ((((nB & 1) * 4 + quad) ^ ((nB >> 1) & 7)) * 16);

    f32x4 acc[4][9] = {};

#define STG_A(J, SB, K0) __builtin_amdgcn_global_load_lds(                    \
        (const AS1 unsigned*)(Ag + aoff0 + (J) * (128 * Cc) + (K0)),          \
        (AS3 unsigned*)&As[SB][((J) * 512 + wave * 64) * 8], 16, 0, 0)
#define STG_B(J, SB, K0) __builtin_amdgcn_global_load_lds(                    \
        (const AS1 unsigned*)(Bg + aoff0 + (J) * (128 * Cc) + (K0)),          \
        (AS3 unsigned*)&Bs[SB][((J) * 512 + wave * 64) * 8], 16, 0, 0)
#define STG_BR(SB, K0) __builtin_amdgcn_global_load_lds(                      \
        (const AS1 unsigned*)(Bg + boffR + (K0)),                             \
        (AS3 unsigned*)&Bs[SB][(1024 + (wave & 1) * 64) * 8], 16, 0, 0)

#define FENCE() asm volatile("" ::: "memory")
#define BAR()   do { FENCE(); __builtin_amdgcn_s_barrier(); FENCE(); } while (0)

    // prologue: tiles 0,1 -> bufs 0,1 (10 loads/thread in flight)
    STG_A(0, 0, 0);  STG_A(1, 0, 0);  STG_B(0, 0, 0);  STG_B(1, 0, 0);  STG_BR(0, 0);
    STG_A(0, 1, 32); STG_A(1, 1, 32); STG_B(0, 1, 32); STG_B(1, 1, 32); STG_BR(1, 32);
    asm volatile("s_waitcnt vmcnt(5)" ::: "memory");   // tile 0 landed
    BAR();

    int buf = 0;
    for (int kt = 0; kt < 24; kt++) {
        const int sb  = (buf == 0) ? 2 : buf - 1;      // (kt+2) % 3
        const int k0n = (kt + 2) << 5;
        const bool st = (kt < 22);
        const char* ap = (const char*)&As[buf][0];
        const char* bp = (const char*)&Bs[buf][0];

        // ---- phase A: stage 3 of tile kt+2; read B frags + a0,a1; 18 MFMA
        if (st) { STG_A(0, sb, k0n); STG_A(1, sb, k0n); STG_B(0, sb, k0n); }
        s16x8 bf[9];
#pragma unroll
        for (int nt = 0; nt < 9; nt++)
            bf[nt] = *(const s16x8*)(bp + bbase + nt * 1024);
        s16x8 a0 = *(const s16x8*)(ap + abase);
        s16x8 a1 = *(const s16x8*)(ap + abase + 1024);
        BAR();                                    // phase gate: reads in flight
        __builtin_amdgcn_sched_barrier(0);
        __builtin_amdgcn_s_setprio(1);
#pragma unroll
        for (int nt = 0; nt < 9; nt++) {
            acc[0][nt] = __builtin_amdgcn_mfma_f32_16x16x32_bf16(a0, bf[nt], acc[0][nt], 0, 0, 0);
            acc[1][nt] = __builtin_amdgcn_mfma_f32_16x16x32_bf16(a1, bf[nt], acc[1][nt], 0, 0, 0);
        }
        __builtin_amdgcn_s_setprio(0);
        BAR();                                    // end of phase A

        // ---- phase B: stage 2 of tile kt+2; read a2,a3; 18 MFMA
        if (st) { STG_B(1, sb, k0n); STG_BR(sb, k0n); }
        s16x8 a2 = *(const s16x8*)(ap + abase + 2048);
        s16x8 a3 = *(const s16x8*)(ap + abase + 3072);
        BAR();
        __builtin_amdgcn_sched_barrier(0);
        __builtin_amdgcn_s_setprio(1);
#pragma unroll
        for (int nt = 0; nt < 9; nt++) {
            acc[2][nt] = __builtin_amdgcn_mfma_f32_16x16x32_bf16(a2, bf[nt], acc[2][nt], 0, 0, 0);
            acc[3][nt] = __builtin_amdgcn_mfma_f32_16x16x32_bf16(a3, bf[nt], acc[3][nt], 0, 0, 0);
        }
        __builtin_amdgcn_s_setprio(0);

        // ---- publish tile kt+1: counted wait (tile kt+2 stays in flight)
        if (kt < 23) {
            if (kt <= 21) asm volatile("s_waitcnt vmcnt(5)" ::: "memory");
            else          asm volatile("s_waitcnt vmcnt(0)" ::: "memory");
            BAR();
        }
        buf = (buf == 2) ? 0 : buf + 1;
    }

    // ---- epilogue: orphan-pair exchange (tile8 <-> tile9 across wc) ----
    // scr = As[0..1] (32 KiB); no conflict with final tiles (buf 2).
    __syncthreads();
    float* scr = (float*)&As[0][0];
    if (wc == 0) {
#pragma unroll
        for (int mt = 0; mt < 4; mt++)
#pragma unroll
            for (int r = 0; r < 4; r++)
                scr[((wr * 4 + mt) * 16 + quad * 4 + r) * 16 + l16] = acc[mt][8][r];
    } else {
#pragma unroll
        for (int mt = 0; mt < 4; mt++)
#pragma unroll
            for (int r = 0; r < 4; r++)
                scr[(((4 + wr) * 4 + mt) * 16 + quad * 4 + r) * 16 + l16] = acc[mt][0][r];
    }
    __syncthreads();

    auto write_epi = [&](auto WCC) {
        constexpr int WC = decltype(WCC)::value;
        constexpr int PO = WC ? 0 : 8;          // own orphan local tile
#pragma unroll
        for (int mt = 0; mt < 4; mt++) {
#pragma unroll
            for (int r = 0; r < 4; r++) {
                const int row = bm + wr * 64 + mt * 16 + quad * 4 + r;
                const int t = row & (Tt - 1);
                short* cp = Cq + (size_t)row * QKV_N + bn + WC * 144;
                // full pairs within this wave (local even tile p = WC + 2*pp)
#pragma unroll
                for (int pp = 0; pp < 4; pp++) {
                    constexpr int PBASE = WC;   // keeps p compile-time
                    const int p = PBASE + 2 * pp;
                    const int g = gt0 + WC * 9 + p;     // global even tile
                    float x1, x2;
                    switch (pp) {               // constant acc indices
                        case 0: x1 = acc[mt][PBASE + 0][r]; x2 = acc[mt][PBASE + 1][r]; break;
                        case 1: x1 = acc[mt][PBASE + 2][r]; x2 = acc[mt][PBASE + 3][r]; break;
                        case 2: x1 = acc[mt][PBASE + 4][r]; x2 = acc[mt][PBASE + 5][r]; break;
                        default: x1 = acc[mt][PBASE + 6][r]; x2 = acc[mt][PBASE + 7][r]; break;
                    }
                    if (g < 96) {                       // q or k: rotate
                        const int i0 = ((g & 2) ? 16 : 0) + l16;
                        const float2 c0 = cs[t * 32 + i0];
                        const float sc = (g < 48) ? 0.125f : 1.0f;
                        cp[p * 16 + l16]       = f2bf((x1 * c0.x + x2 * c0.y) * sc);
                        cp[(p + 1) * 16 + l16] = f2bf((-x1 * c0.y + x2 * c0.x) * sc);
                    } else {                            // v: plain
                        cp[p * 16 + l16]       = f2bf(x1);
                        cp[(p + 1) * 16 + l16] = f2bf(x2);
                    }
                }
                // orphan pair (gt0+8, gt0+9): partner value via LDS
                const float xo = acc[mt][PO][r];
                const float xp = scr[((((WC ^ 1) * 4 + wr) * 4 + mt) * 16 + quad * 4 + r) * 16 + l16];
                const int ge = gt0 + 8;                 // even tile of the pair
                if constexpr (WC == 0) {                // writes tile8 (x1 side)
                    if (ge < 96) {
                        const int i0 = ((ge & 2) ? 16 : 0) + l16;
                        const float2 c0 = cs[t * 32 + i0];
                        const float sc = (ge < 48) ? 0.125f : 1.0f;
                        cp[8 * 16 + l16] = f2bf((xo * c0.x + xp * c0.y) * sc);
                    } else {
                        cp[8 * 16 + l16] = f2bf(xo);
                    }
                } else {                                // writes tile9 (x2 side)
                    if (ge < 96) {
                        const int i0 = ((ge & 2) ? 16 : 0) + l16;
                        const float2 c0 = cs[t * 32 + i0];
                        const float sc = (ge < 48) ? 0.125f : 1.0f;
                        cp[l16] = f2bf((-xp * c0.y + xo * c0.x) * sc);
                    } else {
                        cp[l16] = f2bf(xo);
                    }
                }
            }
        }
    };
    if (wc == 0) write_epi(IC<0>{});
    else         write_epi(IC<1>{});
#undef STG_A
#undef STG_B
#undef STG_BR
#undef FENCE
#undef BAR
}

// ---------------------------------------------------------------------------
// Flash attention v3 (S^T formulation):
//   - process_pair fuses both q-tiles on shared K/V fragment reads.
//   - P converted with v_perm_b32 packed truncation.
//   - P scratch aliases this wave's own store rows: qb in Ks[buf^1],
//     qa in Vs[buf^1].
// Complementary q-block pairing: 768 equal blocks = 3/CU.
// T5 s_setprio(1) around the MFMA clusters (banked win, R4: -4.5us total).
// ---------------------------------------------------------------------------
#define KSP 72
#define VSP 72

__global__ __launch_bounds__(256, 3) void flash_attn(const short* __restrict__ qkv,
                                                     short* __restrict__ y) {
    __shared__ short Ks[2][64 * KSP];
    __shared__ short Vs[2][64 * VSP];

    const int wave = threadIdx.x >> 6;
    const int lane = threadIdx.x & 63;
    const int l16  = lane & 15;
    const int quad = lane >> 4;

    const int pair = blockIdx.x / 96;     // 0..7
    const int bh   = blockIdx.x % 96;
    const int h = bh % Hh;
    const int b = bh / Hh;
    const int qa_blk = pair;
    const int qb_blk = 15 - pair;
    const int q0a = qa_blk * 64 + wave * 16;
    const int q0b = qb_blk * 64 + wave * 16;

    s16x8 qfa[2], qfb[2];
    {
        const short* qpa = qkv + (size_t)(b * Tt + q0a + l16) * QKV_N + h * Dd + quad * 8;
        const short* qpb = qkv + (size_t)(b * Tt + q0b + l16) * QKV_N + h * Dd + quad * 8;
        qfa[0] = *(const s16x8*)qpa;  qfa[1] = *(const s16x8*)(qpa + 32);
        qfb[0] = *(const s16x8*)qpb;  qfb[1] = *(const s16x8*)(qpb + 32);
    }

    f32x4 oa[4] = {}, ob[4] = {};
    float la = 0.f, lb = 0.f;

    const int krow = threadIdx.x >> 2;
    const int kd0  = (threadIdx.x & 3) * 16;
    const int key2 = (threadIdx.x & 31) * 2;
    const int dv0  = (threadIdx.x >> 5) * 8;

    s16x8 pk0, pk1, pv0, pv1;
    auto load_tile = [&](int kbase) {
        const short* kp = qkv + (size_t)(b * Tt + kbase + krow) * QKV_N + Cc + h * Dd + kd0;
        pk0 = *(const s16x8*)kp;
        pk1 = *(const s16x8*)(kp + 8);
        const short* vp = qkv + (size_t)(b * Tt + kbase + key2) * QKV_N + 2 * Cc + h * Dd + dv0;
        pv0 = *(const s16x8*)vp;
        pv1 = *(const s16x8*)(vp + QKV_N);
    };
    auto store_tile = [&](int buf) {
        *(s16x8*)&Ks[buf][krow * KSP + kd0]     = pk0;
        *(s16x8*)&Ks[buf][krow * KSP + kd0 + 8] = pk1;
#pragma unroll
        for (int j = 0; j < 8; j++) {
            ushort2 w; w.x = (unsigned short)pv0[j]; w.y = (unsigned short)pv1[j];
            *(ushort2*)&Vs[buf][(dv0 + j) * VSP + key2] = w;
        }
    };

    auto process_pair = [&](int buf, int kbase, bool mask_a) {
        short* pwb = &Ks[buf ^ 1][wave * 16 * KSP];
        short* pwa = &Vs[buf ^ 1][wave * 16 * VSP];
        f32x4 eb[4], ea[4];
        __builtin_amdgcn_s_setprio(1);          // T5: QK^T MFMA cluster
#pragma unroll
        for (int g = 0; g < 4; g++) {
            s16x8 kf0 = *(const s16x8*)&Ks[buf][(g * 16 + l16) * KSP + quad * 8];
            s16x8 kf1 = *(const s16x8*)&Ks[buf][(g * 16 + l16) * KSP + 32 + quad * 8];
            f32x4 zb = {}, za = {};
            zb = __builtin_amdgcn_mfma_f32_16x16x32_bf16(kf0, qfb[0], zb, 0, 0, 0);
            zb = __builtin_amdgcn_mfma_f32_16x16x32_bf16(kf1, qfb[1], zb, 0, 0, 0);
            za = __builtin_amdgcn_mfma_f32_16x16x32_bf16(kf0, qfa[0], za, 0, 0, 0);
            za = __builtin_amdgcn_mfma_f32_16x16x32_bf16(kf1, qfa[1], za, 0, 0, 0);
            eb[g] = zb; ea[g] = za;
        }
        __builtin_amdgcn_s_setprio(0);
        float rsb = 0.f, rsa = 0.f;
#pragma unroll
        for (int g = 0; g < 4; g++) {
#pragma unroll
            for (int r = 0; r < 4; r++) {
                float pb = __expf(eb[g][r]); rsb += pb; eb[g][r] = pb;
                float pa = __expf(ea[g][r]);
                if (mask_a) pa = (kbase + g * 16 + quad * 4 + r <= q0a + l16) ? pa : 0.0f;
                rsa += pa; ea[g][r] = pa;
            }
            uint2 ub, ua;
            ub.x = pkt(eb[g][1], eb[g][0]); ub.y = pkt(eb[g][3], eb[g][2]);
            ua.x = pkt(ea[g][1], ea[g][0]); ua.y = pkt(ea[g][3], ea[g][2]);
            *(uint2*)&pwb[l16 * KSP + g * 16 + quad * 4] = ub;
            *(uint2*)&pwa[l16 * VSP + g * 16 + quad * 4] = ua;
        }
        lb += rsb; la += rsa;
        __builtin_amdgcn_s_setprio(1);          // T5: PV MFMA cluster
#pragma unroll
        for (int c = 0; c < 2; c++) {
            s16x8 pbb = *(const s16x8*)&pwb[l16 * KSP + c * 32 + quad * 8];
            s16x8 pba = *(const s16x8*)&pwa[l16 * VSP + c * 32 + quad * 8];
#pragma unroll
            for (int nc = 0; nc < 4; nc++) {
                s16x8 vb = *(const s16x8*)&Vs[buf][(nc * 16 + l16) * VSP + c * 32 + quad * 8];
                ob[nc] = __builtin_amdgcn_mfma_f32_16x16x32_bf16(vb, pbb, ob[nc], 0, 0, 0);
                oa[nc] = __builtin_amdgcn_mfma_f32_16x16x32_bf16(vb, pba, oa[nc], 0, 0, 0);
            }
        }
        __builtin_amdgcn_s_setprio(0);
    };

    auto process_single = [&](int buf, int kbase, bool masked) {
        short* pw = &Ks[buf ^ 1][wave * 16 * KSP];
        f32x4 e[4];
        __builtin_amdgcn_s_setprio(1);          // T5: QK^T MFMA cluster
#pragma unroll
        for (int g = 0; g < 4; g++) {
            s16x8 kf0 = *(const s16x8*)&Ks[buf][(g * 16 + l16) * KSP + quad * 8];
            s16x8 kf1 = *(const s16x8*)&Ks[buf][(g * 16 + l16) * KSP + 32 + quad * 8];
            f32x4 z = {};
            z = __builtin_amdgcn_mfma_f32_16x16x32_bf16(kf0, qfb[0], z, 0, 0, 0);
            z = __builtin_amdgcn_mfma_f32_16x16x32_bf16(kf1, qfb[1], z, 0, 0, 0);
            e[g] = z;
        }
        __builtin_amdgcn_s_setprio(0);
        float rs = 0.f;
#pragma unroll
        for (int g = 0; g < 4; g++) {
#pragma unroll
            for (int r = 0; r < 4; r++) {
                float p = __expf(e[g][r]);
                if (masked) p = (kbase + g * 16 + quad * 4 + r <= q0b + l16) ? p : 0.0f;
                rs += p; e[g][r] = p;
            }
            uint2 u;
            u.x = pkt(e[g][1], e[g][0]); u.y = pkt(e[g][3], e[g][2]);
            *(uint2*)&pw[l16 * KSP + g * 16 + quad * 4] = u;
        }
        lb += rs;
        __builtin_amdgcn_s_setprio(1);          // T5: PV MFMA cluster
#pragma unroll
        for (int c = 0; c < 2; c++) {
            s16x8 pb = *(const s16x8*)&pw[l16 * KSP + c * 32 + quad * 8];
#pragma unroll
            for (int nc = 0; nc < 4; nc++) {
                s16x8 vb = *(const s16x8*)&Vs[buf][(nc * 16 + l16) * VSP + c * 32 + quad * 8];
                ob[nc] = __builtin_amdgcn_mfma_f32_16x16x32_bf16(vb, pb, ob[nc], 0, 0, 0);
            }
        }
        __builtin_amdgcn_s_setprio(0);
    };

    load_tile(0);
    store_tile(0);
    for (int kt = 0; kt <= qb_blk; kt++) {
        __syncthreads();
        const int nb = (kt < qb_blk) ? (kt + 1) * 64 : qb_blk * 64;
        load_tile(nb);
        const int buf = kt & 1;
        const int kbase = kt * 64;
        if (kt <= qa_blk)
            process_pair(buf, kbase, kt == qa_blk);
        else
            process_single(buf, kbase, kt == qb_blk);
        store_tile(buf ^ 1);
    }

    float sa = la; sa += __shfl_xor(sa, 16, 64); sa += __shfl_xor(sa, 32, 64);
    float sb = lb; sb += __shfl_xor(sb, 16, 64); sb += __shfl_xor(sb, 32, 64);
    const float inva = 1.0f / sa;
    const float invb = 1.0f / sb;
    short* ypa = y + (size_t)(b * Tt + q0a + l16) * Cc + h * Dd + quad * 4;
    short* ypb = y + (size_t)(b * Tt + q0b + l16) * Cc + h * Dd + quad * 4;
#pragma unroll
    for (int nc = 0; nc < 4; nc++) {
        s16x4 va, vb2;
#pragma unroll
        for (int r = 0; r < 4; r++) {
            va[r]  = f2bf(oa[nc][r] * inva);
            vb2[r] = f2bf(ob[nc][r] * invb);
        }
        *(s16x4*)&ypa[nc * 16] = va;
        *(s16x4*)&ypb[nc * 16] = vb2;
    }
}

// ---------------------------------------------------------------------------
extern "C" void kernel_launch(void* const* d_in, const int* in_sizes, int n_in,
                              void* d_out, int out_size, void* d_ws, size_t ws_size,
                              hipStream_t stream) {
    const float* x      = (const float*)d_in[0];
    const float* w_qkv  = (const float*)d_in[1];
    const float* w_proj = (const float*)d_in[2];
    float* out = (float*)d_out;

    float2* cs    = (float2*)d_ws;                         // 1024*32 float2
    short* xb     = (short*)(cs + Tt * 32);                // 8192x768
    short* wqkvb  = xb + (size_t)M_ROWS * Cc;              // 2304x768 (sigma-permuted q/k rows)
    short* wprojb = wqkvb + (size_t)QKV_N * Cc;            // 768x768
    short* qkvb   = wprojb + (size_t)Cc * Cc;              // 8192x2304
    short* yb     = qkvb + (size_t)M_ROWS * QKV_N;         // 8192x768

    prep_kernel<<<PREP_THREADS / 256, 256, 0, stream>>>(
        x, w_qkv, w_proj, xb, wqkvb, wprojb, cs);

    // qkv = x @ w_qkv.T, fused RoPE + q-scale (bf16 out): 256 blocks = 1/CU,
    // m201-style fine-phase schedule (per-phase barrier pairs + counted vmcnt)
    qkv_gemm_fine<<<256, 512, 0, stream>>>(xb, wqkvb, qkvb, cs);

    flash_attn<<<96 * 8, 256, 0, stream>>>(qkvb, yb);

    // out = y @ w_proj.T (fp32 out): 512 blocks = 2/CU exact
    gemm_nt_mfma<0, 96><<<512, 256, 0, stream>>>(
        yb, wprojb, out, nullptr, M_ROWS, Cc, Cc, Cc / 96);
}

// Round 6
// 162.384 us; speedup vs baseline: 1.0975x; 1.0975x over previous
//
#include <hip/hip_runtime.h>
#include <hip/hip_bf16.h>

// Problem constants (B,T,C,H) = (8,1024,768,12), D=64
#define Bb 8
#define Tt 1024
#define Cc 768
#define Hh 12
#define Dd 64
#define M_ROWS (Bb * Tt)      // 8192
#define QKV_N (3 * Cc)        // 2304

typedef __attribute__((ext_vector_type(8))) short s16x8;   // 8 x bf16
typedef __attribute__((ext_vector_type(4))) short s16x4;   // 4 x bf16
typedef __attribute__((ext_vector_type(4))) float f32x4;

#define AS1 __attribute__((address_space(1)))
#define AS3 __attribute__((address_space(3)))

static __device__ __forceinline__ short f2bf(float f) {
    union { float f; unsigned u; } v; v.f = f;
    unsigned r = (v.u + 0x7fffu + ((v.u >> 16) & 1u)) >> 16;  // RNE
    return (short)r;
}
// two f32 -> packed bf16x2 (TRUNCATION) in one v_perm_b32
static __device__ __forceinline__ unsigned pkt(float hi, float lo) {
    union { float f; unsigned u; } a, b; a.f = hi; b.f = lo;
    return __builtin_amdgcn_perm(a.u, b.u, 0x07060302u);
}

// ---------------------------------------------------------------------------
// Prep: fp32->bf16 casts + RoPE cos/sin table, one launch.
// wqkv rows are PERMUTED for q/k sections (sigma = row^0x30 for within-head
// quadrants 1,2): RoPE partners (i,i+32) become ADJACENT 16-col tiles in the
// qkv output, so any 32-col-aligned wave tile holds complete rotation pairs.
// Q.K is invariant (same sigma on q and k); v rows untouched.
// ---------------------------------------------------------------------------
static __device__ __forceinline__ void cast8(const float* __restrict__ in,
                                             short* __restrict__ out, int i) {
    const float4 a = ((const float4*)in)[i * 2];
    const float4 b = ((const float4*)in)[i * 2 + 1];
    s16x8 f;
    f[0] = f2bf(a.x); f[1] = f2bf(a.y); f[2] = f2bf(a.z); f[3] = f2bf(a.w);
    f[4] = f2bf(b.x); f[5] = f2bf(b.y); f[6] = f2bf(b.z); f[7] = f2bf(b.w);
    ((s16x8*)out)[i] = f;
}

#define S1 (M_ROWS * Cc / 8)   // 786432
#define S2 (QKV_N * Cc / 8)    // 221184
#define S3 (Cc * Cc / 8)       // 73728
#define SROPE (Tt * 32)        // 32768
#define PREP_THREADS (S1 + S2 + S3 + SROPE)  // 1114112 = 4352 * 256

__global__ __launch_bounds__(256) void prep_kernel(const float* __restrict__ x,
                                                   const float* __restrict__ wqkv,
                                                   const float* __restrict__ wproj,
                                                   short* __restrict__ xb,
                                                   short* __restrict__ wqkvb,
                                                   short* __restrict__ wprojb,
                                                   float2* __restrict__ cs) {
    int idx = blockIdx.x * blockDim.x + threadIdx.x;
    if (idx < S1) { cast8(x, xb, idx); return; }
    idx -= S1;
    if (idx < S2) {
        // permuted cast for wqkv: position-row n holds original row tau(n)
        int row = idx / 96;          // 768/8 = 96 chunks per row
        int c8  = idx - row * 96;
        int q2 = (row >> 4) & 3;
        int src = (row < 2 * Cc && (q2 == 1 || q2 == 2)) ? (row ^ 0x30) : row;
        const float4 a = ((const float4*)(wqkv + (size_t)src * Cc))[c8 * 2];
        const float4 b = ((const float4*)(wqkv + (size_t)src * Cc))[c8 * 2 + 1];
        s16x8 f;
        f[0] = f2bf(a.x); f[1] = f2bf(a.y); f[2] = f2bf(a.z); f[3] = f2bf(a.w);
        f[4] = f2bf(b.x); f[5] = f2bf(b.y); f[6] = f2bf(b.z); f[7] = f2bf(b.w);
        ((s16x8*)wqkvb)[idx] = f;
        return;
    }
    idx -= S2;
    if (idx < S3) { cast8(wproj, wprojb, idx); return; }
    idx -= S3;
    {
        int t = idx >> 5, i = idx & 31;
        float inv_freq = exp2f(-0.41524101186092037f * (float)i);  // log2(1e4)/32
        float fr = (float)t * inv_freq;
        float2 v; v.x = cosf(fr); v.y = sinf(fr);
        cs[idx] = v;
    }
}

// ---------------------------------------------------------------------------
// bf16 MFMA GEMM (NT): out[m][n] = sum_k A[m][k] * B[n][k]
// 128 x TN tile, BK=32, waves in 2x2 grid: each wave 64 rows x TN/2 cols.
// qkv TN=192 -> 768 blocks = 3/CU. Double-buffered global_load_lds pipeline
// (1 barrier/iter) + source-side XOR swizzle -> conflict-free ds_read_b128.
// XCD bm-stripe swizzle. MODE 1: bf16 out + fused RoPE epilogue.
// NOTE (R1-R5 post-mortem): ALL deep-pipeline variants lost (coarse counted
// vmcnt 51-55us; fine per-phase barrier-pairs 56us; vs 43.3us here). At this
// shape the 3-blocks/CU implicit overlap (m114) beats hand schedules.
// GEMM pipelining on this kernel is permanently abandoned.
// ---------------------------------------------------------------------------
template <int MODE, int TN>
__global__ __launch_bounds__(256, 3) void gemm_nt_mfma(const short* __restrict__ A,
                                                       const short* __restrict__ B,
                                                       void* __restrict__ Cout,
                                                       const float2* __restrict__ cs,
                                                       int M, int N, int K, int nblocks) {
    __shared__ short As[2][128 * 32];
    __shared__ short Bs[2][TN * 32];
    constexpr int NTW = TN / 32;   // col-tiles per wave

    const int wave = threadIdx.x >> 6;
    const int lane = threadIdx.x & 63;
    const int l16  = lane & 15;
    const int quad = lane >> 4;
    const int wr = wave >> 1;      // 0,1 row half
    const int wc = wave & 1;       // 0,1 col half

    // XCD-aware swizzle (M/128 divisible by 8)
    const int mb8  = (M >> 7) >> 3;
    const int xcd  = blockIdx.x & 7;
    const int slot = blockIdx.x >> 3;
    const int bm = (xcd * mb8 + slot / nblocks) * 128;
    const int bn = (slot % nblocks) * TN;

    f32x4 acc[4][NTW] = {};

    auto stage = [&](int k0, int buf) {
#pragma unroll
        for (int j = 0; j < 2; j++) {                 // A: 512 chunks
            const int D = j * 256 + wave * 64 + lane;
            const int G = D >> 3;
            const int s = (G << 3) | ((D & 7) ^ (G & 7));
            const int m = s >> 2, c4 = (s & 3) * 8;
            __builtin_amdgcn_global_load_lds(
                (const AS1 unsigned*)(A + (size_t)(bm + m) * K + k0 + c4),
                (AS3 unsigned*)&As[buf][(j * 256 + wave * 64) * 8], 16, 0, 0);
        }
        constexpr int BCH = TN * 4;                   // B chunks
#pragma unroll
        for (int j = 0; j < (BCH + 255) / 256; j++) {
            if (BCH % 256 == 0 || j * 256 + wave * 64 < BCH) {  // wave-uniform
                const int D = j * 256 + wave * 64 + lane;
                const int G = D >> 3;
                const int s = (G << 3) | ((D & 7) ^ (G & 7));
                const int m = s >> 2, c4 = (s & 3) * 8;
                __builtin_amdgcn_global_load_lds(
                    (const AS1 unsigned*)(B + (size_t)(bn + m) * K + k0 + c4),
                    (AS3 unsigned*)&Bs[buf][(j * 256 + wave * 64) * 8], 16, 0, 0);
            }
        }
    };

    const int nIter = K >> 5;   // K/32
    stage(0, 0);
    for (int kt = 0; kt < nIter; kt++) {
        const int buf = kt & 1;
        __syncthreads();                       // drains loads for tile kt
        if (kt + 1 < nIter) stage((kt + 1) << 5, buf ^ 1);

        s16x8 af[4];
#pragma unroll
        for (int mt = 0; mt < 4; mt++) {
            const int m = wr * 64 + mt * 16 + l16;
            const int d = ((m & 1) * 4 + quad) ^ ((m >> 1) & 7);
            af[mt] = *(const s16x8*)&As[buf][(m >> 1) * 64 + d * 8];
        }
#pragma unroll
        for (int nt = 0; nt < NTW; nt++) {
            const int n = wc * (TN / 2) + nt * 16 + l16;
            const int d = ((n & 1) * 4 + quad) ^ ((n >> 1) & 7);
            s16x8 bf = *(const s16x8*)&Bs[buf][(n >> 1) * 64 + d * 8];
#pragma unroll
            for (int mt = 0; mt < 4; mt++)
                acc[mt][nt] = __builtin_amdgcn_mfma_f32_16x16x32_bf16(
                    af[mt], bf, acc[mt][nt], 0, 0, 0);
        }
    }

    if constexpr (MODE == 0) {
#pragma unroll
        for (int mt = 0; mt < 4; mt++)
#pragma unroll
            for (int r = 0; r < 4; r++) {
                const size_t row = bm + wr * 64 + mt * 16 + quad * 4 + r;
#pragma unroll
                for (int nt = 0; nt < NTW; nt++)
                    ((float*)Cout)[row * N + bn + wc * (TN / 2) + nt * 16 + l16] =
                        acc[mt][nt][r];
            }
    } else {
        const bool is_v = (bn >= 2 * Cc);
        if (is_v) {
#pragma unroll
            for (int mt = 0; mt < 4; mt++)
#pragma unroll
                for (int r = 0; r < 4; r++) {
                    const size_t row = bm + wr * 64 + mt * 16 + quad * 4 + r;
#pragma unroll
                    for (int nt = 0; nt < NTW; nt++)
                        ((short*)Cout)[row * N + bn + wc * (TN / 2) + nt * 16 + l16] =
                            f2bf(acc[mt][nt][r]);
                }
        } else {
            const float scale = (bn < Cc) ? 0.125f : 1.0f;  // q gets 1/sqrt(D)
#pragma unroll
            for (int mt = 0; mt < 4; mt++) {
#pragma unroll
                for (int r = 0; r < 4; r++) {
                    const int row = bm + wr * 64 + mt * 16 + quad * 4 + r;
                    const int t = row & (Tt - 1);
                    short* cp = (short*)Cout + (size_t)row * N + bn + wc * (TN / 2);
#pragma unroll
                    for (int p = 0; p < NTW; p += 2) {   // adjacent-tile pairs
                        const int g = wc * NTW + p;       // global col-tile (even)
                        const int i0 = ((g & 2) ? 16 : 0) + l16;
                        const float2 c0 = cs[t * 32 + i0];
                        const float x1 = acc[mt][p][r];
                        const float x2 = acc[mt][p + 1][r];
                        cp[p * 16 + l16]        = f2bf((x1 * c0.x + x2 * c0.y) * scale);
                        cp[(p + 1) * 16 + l16]  = f2bf((-x1 * c0.y + x2 * c0.x) * scale);
                    }
                }
            }
        }
    }
}

// ---------------------------------------------------------------------------
// PROJ GEMM, double-pumped K-loop (R6):
//   proj has 1/3 of qkv's FLOPs but ran the SAME 24 barrier-drain rounds at
//   only 2 blocks/CU residency -> drain-bound (~1.5us/round estimate).
//   Fix: stage TWO BK=32 tiles per round into two buffer sets (4 bufs x
//   14 KB = 56 KB -> still exactly 2 blocks/CU, zero residency loss, zero
//   new swizzle math) and run ONE __syncthreads per 2 tiles -> 12 rounds.
//   Per-tile staging + fragment formulas are verbatim from gemm_nt_mfma.
//   MODE 0 epilogue (fp32 out). TN=96, grid 512 = 2/CU exact.
// ---------------------------------------------------------------------------
template <int TN>
__global__ __launch_bounds__(256, 2) void gemm_nt_proj2(const short* __restrict__ A,
                                                        const short* __restrict__ B,
                                                        float* __restrict__ Cout,
                                                        int M, int N, int K, int nblocks) {
    __shared__ short As[2][2][128 * 32];   // [pair][tile]
    __shared__ short Bs[2][2][TN * 32];
    constexpr int NTW = TN / 32;   // col-tiles per wave

    const int wave = threadIdx.x >> 6;
    const int lane = threadIdx.x & 63;
    const int l16  = lane & 15;
    const int quad = lane >> 4;
    const int wr = wave >> 1;      // 0,1 row half
    const int wc = wave & 1;       // 0,1 col half

    // XCD-aware swizzle (M/128 divisible by 8)
    const int mb8  = (M >> 7) >> 3;
    const int xcd  = blockIdx.x & 7;
    const int slot = blockIdx.x >> 3;
    const int bm = (xcd * mb8 + slot / nblocks) * 128;
    const int bn = (slot % nblocks) * TN;

    f32x4 acc[4][NTW] = {};

    auto stage = [&](int k0, int p, int t) {
#pragma unroll
        for (int j = 0; j < 2; j++) {                 // A: 512 chunks
            const int D = j * 256 + wave * 64 + lane;
            const int G = D >> 3;
            const int s = (G << 3) | ((D & 7) ^ (G & 7));
            const int m = s >> 2, c4 = (s & 3) * 8;
            __builtin_amdgcn_global_load_lds(
                (const AS1 unsigned*)(A + (size_t)(bm + m) * K + k0 + c4),
                (AS3 unsigned*)&As[p][t][(j * 256 + wave * 64) * 8], 16, 0, 0);
        }
        constexpr int BCH = TN * 4;                   // B chunks
#pragma unroll
        for (int j = 0; j < (BCH + 255) / 256; j++) {
            if (BCH % 256 == 0 || j * 256 + wave * 64 < BCH) {  // wave-uniform
                const int D = j * 256 + wave * 64 + lane;
                const int G = D >> 3;
                const int s = (G << 3) | ((D & 7) ^ (G & 7));
                const int m = s >> 2, c4 = (s & 3) * 8;
                __builtin_amdgcn_global_load_lds(
                    (const AS1 unsigned*)(B + (size_t)(bn + m) * K + k0 + c4),
                    (AS3 unsigned*)&Bs[p][t][(j * 256 + wave * 64) * 8], 16, 0, 0);
            }
        }
    };

    const int nPair = K >> 6;   // K/64 double-rounds (768 -> 12)
    stage(0, 0, 0);
    stage(32, 0, 1);
    for (int it = 0; it < nPair; it++) {
        const int p = it & 1;
        __syncthreads();                       // drains both tiles of pair it
        if (it + 1 < nPair) {
            stage((2 * it + 2) << 5, p ^ 1, 0);
            stage((2 * it + 3) << 5, p ^ 1, 1);
        }
#pragma unroll
        for (int t = 0; t < 2; t++) {
            s16x8 af[4];
#pragma unroll
            for (int mt = 0; mt < 4; mt++) {
                const int m = wr * 64 + mt * 16 + l16;
                const int d = ((m & 1) * 4 + quad) ^ ((m >> 1) & 7);
                af[mt] = *(const s16x8*)&As[p][t][(m >> 1) * 64 + d * 8];
            }
#pragma unroll
            for (int nt = 0; nt < NTW; nt++) {
                const int n = wc * (TN / 2) + nt * 16 + l16;
                const int d = ((n & 1) * 4 + quad) ^ ((n >> 1) & 7);
                s16x8 bf = *(const s16x8*)&Bs[p][t][(n >> 1) * 64 + d * 8];
#pragma unroll
                for (int mt = 0; mt < 4; mt++)
                    acc[mt][nt] = __builtin_amdgcn_mfma_f32_16x16x32_bf16(
                        af[mt], bf, acc[mt][nt], 0, 0, 0);
            }
        }
    }

#pragma unroll
    for (int mt = 0; mt < 4; mt++)
#pragma unroll
        for (int r = 0; r < 4; r++) {
            const size_t row = bm + wr * 64 + mt * 16 + quad * 4 + r;
#pragma unroll
            for (int nt = 0; nt < NTW; nt++)
                Cout[row * N + bn + wc * (TN / 2) + nt * 16 + l16] = acc[mt][nt][r];
        }
}

// ---------------------------------------------------------------------------
// Flash attention v3 (S^T formulation):
//   - process_pair fuses both q-tiles on shared K/V fragment reads.
//   - P converted with v_perm_b32 packed truncation.
//   - P scratch aliases this wave's own store rows: qb in Ks[buf^1],
//     qa in Vs[buf^1].
// Complementary q-block pairing: 768 equal blocks = 3/CU.
// T5 s_setprio(1) around the MFMA clusters (banked win, R4: -4.5us total).
// ---------------------------------------------------------------------------
#define KSP 72
#define VSP 72

__global__ __launch_bounds__(256, 3) void flash_attn(const short* __restrict__ qkv,
                                                     short* __restrict__ y) {
    __shared__ short Ks[2][64 * KSP];
    __shared__ short Vs[2][64 * VSP];

    const int wave = threadIdx.x >> 6;
    const int lane = threadIdx.x & 63;
    const int l16  = lane & 15;
    const int quad = lane >> 4;

    const int pair = blockIdx.x / 96;     // 0..7
    const int bh   = blockIdx.x % 96;
    const int h = bh % Hh;
    const int b = bh / Hh;
    const int qa_blk = pair;
    const int qb_blk = 15 - pair;
    const int q0a = qa_blk * 64 + wave * 16;
    const int q0b = qb_blk * 64 + wave * 16;

    s16x8 qfa[2], qfb[2];
    {
        const short* qpa = qkv + (size_t)(b * Tt + q0a + l16) * QKV_N + h * Dd + quad * 8;
        const short* qpb = qkv + (size_t)(b * Tt + q0b + l16) * QKV_N + h * Dd + quad * 8;
        qfa[0] = *(const s16x8*)qpa;  qfa[1] = *(const s16x8*)(qpa + 32);
        qfb[0] = *(const s16x8*)qpb;  qfb[1] = *(const s16x8*)(qpb + 32);
    }

    f32x4 oa[4] = {}, ob[4] = {};
    float la = 0.f, lb = 0.f;

    const int krow = threadIdx.x >> 2;
    const int kd0  = (threadIdx.x & 3) * 16;
    const int key2 = (threadIdx.x & 31) * 2;
    const int dv0  = (threadIdx.x >> 5) * 8;

    s16x8 pk0, pk1, pv0, pv1;
    auto load_tile = [&](int kbase) {
        const short* kp = qkv + (size_t)(b * Tt + kbase + krow) * QKV_N + Cc + h * Dd + kd0;
        pk0 = *(const s16x8*)kp;
        pk1 = *(const s16x8*)(kp + 8);
        const short* vp = qkv + (size_t)(b * Tt + kbase + key2) * QKV_N + 2 * Cc + h * Dd + dv0;
        pv0 = *(const s16x8*)vp;
        pv1 = *(const s16x8*)(vp + QKV_N);
    };
    auto store_tile = [&](int buf) {
        *(s16x8*)&Ks[buf][krow * KSP + kd0]     = pk0;
        *(s16x8*)&Ks[buf][krow * KSP + kd0 + 8] = pk1;
#pragma unroll
        for (int j = 0; j < 8; j++) {
            ushort2 w; w.x = (unsigned short)pv0[j]; w.y = (unsigned short)pv1[j];
            *(ushort2*)&Vs[buf][(dv0 + j) * VSP + key2] = w;
        }
    };

    auto process_pair = [&](int buf, int kbase, bool mask_a) {
        short* pwb = &Ks[buf ^ 1][wave * 16 * KSP];
        short* pwa = &Vs[buf ^ 1][wave * 16 * VSP];
        f32x4 eb[4], ea[4];
        __builtin_amdgcn_s_setprio(1);          // T5: QK^T MFMA cluster
#pragma unroll
        for (int g = 0; g < 4; g++) {
            s16x8 kf0 = *(const s16x8*)&Ks[buf][(g * 16 + l16) * KSP + quad * 8];
            s16x8 kf1 = *(const s16x8*)&Ks[buf][(g * 16 + l16) * KSP + 32 + quad * 8];
            f32x4 zb = {}, za = {};
            zb = __builtin_amdgcn_mfma_f32_16x16x32_bf16(kf0, qfb[0], zb, 0, 0, 0);
            zb = __builtin_amdgcn_mfma_f32_16x16x32_bf16(kf1, qfb[1], zb, 0, 0, 0);
            za = __builtin_amdgcn_mfma_f32_16x16x32_bf16(kf0, qfa[0], za, 0, 0, 0);
            za = __builtin_amdgcn_mfma_f32_16x16x32_bf16(kf1, qfa[1], za, 0, 0, 0);
            eb[g] = zb; ea[g] = za;
        }
        __builtin_amdgcn_s_setprio(0);
        float rsb = 0.f, rsa = 0.f;
#pragma unroll
        for (int g = 0; g < 4; g++) {
#pragma unroll
            for (int r = 0; r < 4; r++) {
                float pb = __expf(eb[g][r]); rsb += pb; eb[g][r] = pb;
                float pa = __expf(ea[g][r]);
                if (mask_a) pa = (kbase + g * 16 + quad * 4 + r <= q0a + l16) ? pa : 0.0f;
                rsa += pa; ea[g][r] = pa;
            }
            uint2 ub, ua;
            ub.x = pkt(eb[g][1], eb[g][0]); ub.y = pkt(eb[g][3], eb[g][2]);
            ua.x = pkt(ea[g][1], ea[g][0]); ua.y = pkt(ea[g][3], ea[g][2]);
            *(uint2*)&pwb[l16 * KSP + g * 16 + quad * 4] = ub;
            *(uint2*)&pwa[l16 * VSP + g * 16 + quad * 4] = ua;
        }
        lb += rsb; la += rsa;
        __builtin_amdgcn_s_setprio(1);          // T5: PV MFMA cluster
#pragma unroll
        for (int c = 0; c < 2; c++) {
            s16x8 pbb = *(const s16x8*)&pwb[l16 * KSP + c * 32 + quad * 8];
            s16x8 pba = *(const s16x8*)&pwa[l16 * VSP + c * 32 + quad * 8];
#pragma unroll
            for (int nc = 0; nc < 4; nc++) {
                s16x8 vb = *(const s16x8*)&Vs[buf][(nc * 16 + l16) * VSP + c * 32 + quad * 8];
                ob[nc] = __builtin_amdgcn_mfma_f32_16x16x32_bf16(vb, pbb, ob[nc], 0, 0, 0);
                oa[nc] = __builtin_amdgcn_mfma_f32_16x16x32_bf16(vb, pba, oa[nc], 0, 0, 0);
            }
        }
        __builtin_amdgcn_s_setprio(0);
    };

    auto process_single = [&](int buf, int kbase, bool masked) {
        short* pw = &Ks[buf ^ 1][wave * 16 * KSP];
        f32x4 e[4];
        __builtin_amdgcn_s_setprio(1);          // T5: QK^T MFMA cluster
#pragma unroll
        for (int g = 0; g < 4; g++) {
            s16x8 kf0 = *(const s16x8*)&Ks[buf][(g * 16 + l16) * KSP + quad * 8];
            s16x8 kf1 = *(const s16x8*)&Ks[buf][(g * 16 + l16) * KSP + 32 + quad * 8];
            f32x4 z = {};
            z = __builtin_amdgcn_mfma_f32_16x16x32_bf16(kf0, qfb[0], z, 0, 0, 0);
            z = __builtin_amdgcn_mfma_f32_16x16x32_bf16(kf1, qfb[1], z, 0, 0, 0);
            e[g] = z;
        }
        __builtin_amdgcn_s_setprio(0);
        float rs = 0.f;
#pragma unroll
        for (int g = 0; g < 4; g++) {
#pragma unroll
            for (int r = 0; r < 4; r++) {
                float p = __expf(e[g][r]);
                if (masked) p = (kbase + g * 16 + quad * 4 + r <= q0b + l16) ? p : 0.0f;
                rs += p; e[g][r] = p;
            }
            uint2 u;
            u.x = pkt(e[g][1], e[g][0]); u.y = pkt(e[g][3], e[g][2]);
            *(uint2*)&pw[l16 * KSP + g * 16 + quad * 4] = u;
        }
        lb += rs;
        __builtin_amdgcn_s_setprio(1);          // T5: PV MFMA cluster
#pragma unroll
        for (int c = 0; c < 2; c++) {
            s16x8 pb = *(const s16x8*)&pw[l16 * KSP + c * 32 + quad * 8];
#pragma unroll
            for (int nc = 0; nc < 4; nc++) {
                s16x8 vb = *(const s16x8*)&Vs[buf][(nc * 16 + l16) * VSP + c * 32 + quad * 8];
                ob[nc] = __builtin_amdgcn_mfma_f32_16x16x32_bf16(vb, pb, ob[nc], 0, 0, 0);
            }
        }
        __builtin_amdgcn_s_setprio(0);
    };

    load_tile(0);
    store_tile(0);
    for (int kt = 0; kt <= qb_blk; kt++) {
        __syncthreads();
        const int nb = (kt < qb_blk) ? (kt + 1) * 64 : qb_blk * 64;
        load_tile(nb);
        const int buf = kt & 1;
        const int kbase = kt * 64;
        if (kt <= qa_blk)
            process_pair(buf, kbase, kt == qa_blk);
        else
            process_single(buf, kbase, kt == qb_blk);
        store_tile(buf ^ 1);
    }

    float sa = la; sa += __shfl_xor(sa, 16, 64); sa += __shfl_xor(sa, 32, 64);
    float sb = lb; sb += __shfl_xor(sb, 16, 64); sb += __shfl_xor(sb, 32, 64);
    const float inva = 1.0f / sa;
    const float invb = 1.0f / sb;
    short* ypa = y + (size_t)(b * Tt + q0a + l16) * Cc + h * Dd + quad * 4;
    short* ypb = y + (size_t)(b * Tt + q0b + l16) * Cc + h * Dd + quad * 4;
#pragma unroll
    for (int nc = 0; nc < 4; nc++) {
        s16x4 va, vb2;
#pragma unroll
        for (int r = 0; r < 4; r++) {
            va[r]  = f2bf(oa[nc][r] * inva);
            vb2[r] = f2bf(ob[nc][r] * invb);
        }
        *(s16x4*)&ypa[nc * 16] = va;
        *(s16x4*)&ypb[nc * 16] = vb2;
    }
}

// ---------------------------------------------------------------------------
extern "C" void kernel_launch(void* const* d_in, const int* in_sizes, int n_in,
                              void* d_out, int out_size, void* d_ws, size_t ws_size,
                              hipStream_t stream) {
    const float* x      = (const float*)d_in[0];
    const float* w_qkv  = (const float*)d_in[1];
    const float* w_proj = (const float*)d_in[2];
    float* out = (float*)d_out;

    float2* cs    = (float2*)d_ws;                         // 1024*32 float2
    short* xb     = (short*)(cs + Tt * 32);                // 8192x768
    short* wqkvb  = xb + (size_t)M_ROWS * Cc;              // 2304x768 (sigma-permuted q/k rows)
    short* wprojb = wqkvb + (size_t)QKV_N * Cc;            // 768x768
    short* qkvb   = wprojb + (size_t)Cc * Cc;              // 8192x2304
    short* yb     = qkvb + (size_t)M_ROWS * QKV_N;         // 8192x768

    prep_kernel<<<PREP_THREADS / 256, 256, 0, stream>>>(
        x, w_qkv, w_proj, xb, wqkvb, wprojb, cs);

    // qkv = x @ w_qkv.T with fused RoPE + q-scale (bf16 out): 768 blocks = 3/CU
    gemm_nt_mfma<1, 192><<<768, 256, 0, stream>>>(
        xb, wqkvb, qkvb, cs, M_ROWS, QKV_N, Cc, QKV_N / 192);

    flash_attn<<<96 * 8, 256, 0, stream>>>(qkvb, yb);

    // out = y @ w_proj.T (fp32 out): 512 blocks = 2/CU exact, double-pumped
    // K-loop (12 barrier rounds instead of 24)
    gemm_nt_proj2<96><<<512, 256, 0, stream>>>(
        yb, wprojb, out, M_ROWS, Cc, Cc, Cc / 96);
}